// Round 7
// baseline (212.577 us; speedup 1.0000x reference)
//
#include <hip/hip_runtime.h>
#include <hip/hip_fp16.h>

// GAT: B=256, N=64, K=12, D=128
// Folding: wq_eff = Wq@wa_q, wk_eff = Wk@wa_k (only score projections used);
// out = (sum_j attn_j nh_j) @ Wv + bv * (sum_j attn_j).
// Self-contained blocks, zero d_ws (R3 post-timing failure = ws handoff race).
//
// R7 theory: R6's 76us is Phase-A double round-trip (VGPR=64 -> compiler
// refetches x[] from global after the reduce/exp chain) + only 4 blocks/CU.
//  - Stage x[j] in LDS as fp16 WHILE loading (x consumed into tj partials
//    immediately -> low liveness -> 13 loads fully in flight); pooling reads
//    back from LDS (no global refetch, no 2nd HBM/L2 round trip).
//  - ROWS 16->8, grid 2048: LDS 30KB/block -> 5 blocks/CU, ~20 waves/CU.
//  - Phase 0/A cross-lane structure kept from R6 (65 shuffles / 2 pairs).

#define B_  256
#define N_  64
#define K_  12
#define D_  128
#define BN  (B_ * N_)          // 16384 (b,n) pairs
#define ROWS 8                 // pairs per block
#define NBLK (BN / ROWS)       // 2048 blocks
#define HB_STRIDE 132          // floats; float4-aligned row stride

struct h4 { __half2 lo, hi; }; // 8B packed fp16 x4

__global__ void __launch_bounds__(256, 4)
fused_kernel(const float* __restrict__ nodes, const float* __restrict__ neigh,
             const float* __restrict__ mask,
             const float* __restrict__ Wq, const float* __restrict__ bq,
             const float* __restrict__ Wk, const float* __restrict__ bk,
             const float* __restrict__ Wv, const float* __restrict__ bv,
             const float* __restrict__ wa_q, const float* __restrict__ wa_k,
             const float* __restrict__ ba_p, float* __restrict__ out) {
    __shared__ float weff[256];               // [0..127] wq_eff | [128..255] wk_eff
    __shared__ h4    stg[4][2][K_][32];       // fp16 staged neighbor vectors
    __shared__ float hb[ROWS * HB_STRIDE];    // pooled hidden rows
    __shared__ float scL[ROWS];               // sum of attn weights per row
    __shared__ float cstS;                    // bq.wa_q + bk.wa_k + ba

    const int t    = threadIdx.x;
    const int wave = t >> 6;
    const int l    = t & 63;

    // ---- Phase 0: weff, 16 lanes per row (8 dims in-lane, 4-stage reduce) ----
    {
        const bool  isQ  = (wave < 2);
        const float* Wm  = isQ ? Wq : Wk;
        const float* wav = isQ ? wa_q : wa_k;
        const int sub    = l & 15;
        const int rquad  = l >> 4;
        const int rbase  = (wave & 1) * 64;
        const int obase  = isQ ? 0 : 128;
        float4 wv0 = ((const float4*)wav)[sub * 2];
        float4 wv1 = ((const float4*)wav)[sub * 2 + 1];
        #pragma unroll 4
        for (int i = 0; i < 16; ++i) {
            int r = rbase + i * 4 + rquad;
            const float4* wr = (const float4*)(Wm + (size_t)r * D_);
            float4 a0 = wr[sub * 2], a1 = wr[sub * 2 + 1];
            float p = a0.x * wv0.x + a0.y * wv0.y + a0.z * wv0.z + a0.w * wv0.w
                    + a1.x * wv1.x + a1.y * wv1.y + a1.z * wv1.z + a1.w * wv1.w;
            p += __shfl_xor(p, 1, 64);
            p += __shfl_xor(p, 2, 64);
            p += __shfl_xor(p, 4, 64);
            p += __shfl_xor(p, 8, 64);
            if (sub == 0) weff[obase + r] = p;
        }
    }
    if (wave == 0) {
        float2 q2  = ((const float2*)bq)[l];
        float2 k2  = ((const float2*)bk)[l];
        float2 aq2 = ((const float2*)wa_q)[l];
        float2 ak2 = ((const float2*)wa_k)[l];
        float c = q2.x * aq2.x + q2.y * aq2.y + k2.x * ak2.x + k2.y * ak2.y;
        #pragma unroll
        for (int m = 1; m < 64; m <<= 1) c += __shfl_xor(c, m, 64);
        if (l == 0) cstS = c + ba_p[0];
    }
    __syncthreads();

    const float cst = cstS;
    const int h = l >> 5;                    // half: which pair of the duo
    const int s = l & 31;                    // lane within pair; dims s*4..s*4+3
    const float4 wqe = ((const float4*)weff)[s];
    const float4 wke = ((const float4*)(weff + 128))[s];

    // ---- Phase A: one iteration, 2 pairs (wave halves) ----
    {
        const int lrow = wave * 2 + h;                 // 0..7 local row
        const int idx  = blockIdx.x * ROWS + lrow;     // (b,n) flat index

        const float4* np = (const float4*)(nodes + (size_t)idx * D_);
        const float4* gp = (const float4*)(neigh + (size_t)idx * (K_ * D_));

        // node vector stays in registers (needed for pooling)
        float4 x0 = np[s];
        float pq = x0.x * wqe.x + x0.y * wqe.y + x0.z * wqe.z + x0.w * wqe.w;

        float tj[K_ + 1];
        tj[0] = pq + x0.x * wke.x + x0.y * wke.y + x0.z * wke.z + x0.w * wke.w;

        // neighbors: load -> tj partial + fp16 LDS stage, consumed immediately
        h4* sp = &stg[wave][h][0][s];
        #pragma unroll
        for (int j = 0; j < K_; ++j) {
            float4 xj = gp[j * 32 + s];
            tj[j + 1] = pq + xj.x * wke.x + xj.y * wke.y
                           + xj.z * wke.z + xj.w * wke.w;
            h4 p;
            p.lo = __floats2half2_rn(xj.x, xj.y);
            p.hi = __floats2half2_rn(xj.z, xj.w);
            sp[j * 32] = p;
        }

        float mval = (s < K_) ? mask[(size_t)idx * K_ + s] : 0.0f;
        unsigned long long mbits = __ballot(mval > 0.5f);

        // 5-stage butterfly within 32-lane halves (xor<32 never crosses)
        #pragma unroll
        for (int m = 1; m < 32; m <<= 1) {
            #pragma unroll
            for (int j = 0; j <= K_; ++j) tj[j] += __shfl_xor(tj[j], m, 64);
        }

        float e[K_ + 1];
        float S = 0.0f;
        #pragma unroll
        for (int j = 0; j <= K_; ++j) {
            float sc = tj[j] + cst;
            sc = (sc >= 0.0f) ? sc : 0.2f * sc;        // LeakyReLU(0.2)
            float mj = (j == 0) ? 1.0f
                     : (((mbits >> (h * 32 + j - 1)) & 1ull) ? 1.0f : 0.0f);
            e[j] = __expf(sc) * mj;                    // masked exp
            S += e[j];
        }
        const float inv = 1.0f / (S + 1e-16f);

        // pooling: node from regs, neighbors back from LDS (L2-free)
        float w0 = e[0] * inv;
        float4 hacc;
        hacc.x = w0 * x0.x;  hacc.y = w0 * x0.y;
        hacc.z = w0 * x0.z;  hacc.w = w0 * x0.w;
        #pragma unroll
        for (int j = 0; j < K_; ++j) {
            h4 p = sp[j * 32];
            float2 a = __half22float2(p.lo);
            float2 b = __half22float2(p.hi);
            float w = e[j + 1] * inv;
            hacc.x += w * a.x;  hacc.y += w * a.y;
            hacc.z += w * b.x;  hacc.w += w * b.y;
        }
        *(float4*)(hb + lrow * HB_STRIDE + s * 4) = hacc;
        if (s == 0) scL[lrow] = S * inv;
    }
    __syncthreads();

    // ---- Phase B: out[8x128] = hb @ Wv + bv*scale ----
    const int rg   = t >> 5;                      // 0..7 (one row per 32-group)
    const int cg   = t & 31;                      // cols cg*4..+3
    const int row0 = blockIdx.x * ROWS;
    const float4* wv4 = (const float4*)Wv;

    float4 acc = make_float4(0.f, 0.f, 0.f, 0.f);
    #pragma unroll 8
    for (int k = 0; k < D_; ++k) {
        float4 b = wv4[k * 32 + cg];
        float  a = hb[rg * HB_STRIDE + k];        // 2-addr broadcast: free
        acc.x += a * b.x;  acc.y += a * b.y;
        acc.z += a * b.z;  acc.w += a * b.w;
    }

    float4 bvv = ((const float4*)bv)[cg];
    float  sc  = scL[rg];
    float4 o;
    o.x = acc.x + bvv.x * sc;  o.y = acc.y + bvv.y * sc;
    o.z = acc.z + bvv.z * sc;  o.w = acc.w + bvv.w * sc;
    *(float4*)(out + (size_t)(row0 + rg) * D_ + cg * 4) = o;
}

// ---------------------------------------------------------------------------
extern "C" void kernel_launch(void* const* d_in, const int* in_sizes, int n_in,
                              void* d_out, int out_size, void* d_ws, size_t ws_size,
                              hipStream_t stream) {
    const float* nodes = (const float*)d_in[0];
    const float* neigh = (const float*)d_in[1];
    const float* mask  = (const float*)d_in[2];
    const float* Wq    = (const float*)d_in[3];
    const float* bq    = (const float*)d_in[4];
    const float* Wk    = (const float*)d_in[5];
    const float* bk    = (const float*)d_in[6];
    const float* Wv    = (const float*)d_in[7];
    const float* bv    = (const float*)d_in[8];
    const float* wa_q  = (const float*)d_in[9];
    const float* wa_k  = (const float*)d_in[10];
    const float* ba    = (const float*)d_in[11];
    float* out = (float*)d_out;

    fused_kernel<<<NBLK, 256, 0, stream>>>(nodes, neigh, mask, Wq, bq, Wk, bk,
                                           Wv, bv, wa_q, wa_k, ba, out);
}